// Round 8
// baseline (186.988 us; speedup 1.0000x reference)
//
#include <hip/hip_runtime.h>

typedef __attribute__((ext_vector_type(8))) short short8;
typedef __attribute__((ext_vector_type(4))) float f32x4;
typedef __attribute__((ext_vector_type(4))) unsigned short u16x4;
typedef unsigned short ushort_t;

#define GLOAD16(gp, sp) __builtin_amdgcn_global_load_lds( \
    (const __attribute__((address_space(1))) void*)(gp),  \
    (__attribute__((address_space(3))) void*)(sp), 16, 0, 0)

#define MFMA(a, b, c) __builtin_amdgcn_mfma_f32_16x16x32_bf16(a, b, c, 0, 0, 0)

__device__ __forceinline__ ushort_t f2b(float f) {
    union { float f; unsigned u; } c; c.f = f;
    unsigned r = (c.u + 0x7FFFu + ((c.u >> 16) & 1u)) >> 16;
    return (ushort_t)r;
}
__device__ __forceinline__ float b2f(ushort_t u) {
    union { unsigned u; float f; } c; c.u = ((unsigned)u) << 16;
    return c.f;
}

// ---------------- fp32 -> bf16 convert ----------------
__global__ void cvt_bf16(const float* __restrict__ in, ushort_t* __restrict__ out, int n) {
    int i = (blockIdx.x * 256 + threadIdx.x) * 4;
    if (i < n) {
        f32x4 v = *(const f32x4*)(in + i);
        u16x4 o;
        #pragma unroll
        for (int j = 0; j < 4; j++) o[j] = f2b(v[j]);
        *(u16x4*)(out + i) = o;
    }
}

// ---------------- fp32 [R][Cc] -> bf16 [Cc][R] transpose ----------------
__global__ __launch_bounds__(256) void transpose_cvt(const float* __restrict__ in,
                                                     ushort_t* __restrict__ out,
                                                     int R, int Cc) {
    __shared__ float tile[32][33];
    int tx = threadIdx.x & 31, ty = threadIdx.x >> 5;
    int c0 = blockIdx.x * 32, r0 = blockIdx.y * 32;
    #pragma unroll
    for (int i = 0; i < 32; i += 8)
        tile[ty + i][tx] = in[(size_t)(r0 + ty + i) * Cc + c0 + tx];
    __syncthreads();
    #pragma unroll
    for (int i = 0; i < 32; i += 8)
        out[(size_t)(c0 + ty + i) * R + r0 + tx] = f2b(tile[tx][ty + i]);
}

// ---------------- bf16 GEMM: C[M][N] = A[M][K] * Bt[N][K]^T ----------------
// 128x128 tile, BK=32, 4 waves. T3+T4: 3-buffer LDS pipeline, depth-2 prefetch,
// COUNTED vmcnt (never 0 in steady state) + raw s_barrier. Tile t+1's loads were
// issued a full iteration before their use -> full latency cover; tile t+2's 4
// loads stay in flight across the barrier.
// 1-D grid, XCD-chunked: xcd owns ny/8 contiguous m-rows (A-panel L2 locality).
#define WAITV4 asm volatile("s_waitcnt vmcnt(4)" ::: "memory")
#define WAITV0 asm volatile("s_waitcnt vmcnt(0)" ::: "memory")
#define SBAR do { __builtin_amdgcn_s_barrier(); __builtin_amdgcn_sched_barrier(0); } while (0)

template <bool F32OUT, bool BIAS>
__global__ __launch_bounds__(256) void gemm_bt(const ushort_t* __restrict__ A,
                                               const ushort_t* __restrict__ Bt,
                                               void* __restrict__ Cout,
                                               const float* __restrict__ bias,
                                               int M, int N, int K, int nx) {
    __shared__ ushort_t lA[3][4096];
    __shared__ ushort_t lB[3][4096];
    const int tid = threadIdx.x;
    const int l = tid & 63, wv = tid >> 6;
    const int g = l >> 4, q16 = l & 15;
    // XCD-chunked block mapping (grid % 8 == 0): xcd owns ry consecutive m-rows.
    const int xcd = blockIdx.x & 7, idx = blockIdx.x >> 3;
    const int ry = (int)(gridDim.x >> 3) / nx;
    const int m0 = (xcd * ry + idx / nx) * 128;
    const int n0 = (idx % nx) * 128;
    const int wr = wv >> 1, wc = wv & 1;

    f32x4 acc[4][4];
    #pragma unroll
    for (int i = 0; i < 4; i++)
        #pragma unroll
        for (int j = 0; j < 4; j++) acc[i][j] = (f32x4){0.f, 0.f, 0.f, 0.f};

    const ushort_t* ga = A + (size_t)(m0 + wv * 32 + (l >> 2)) * K + (l & 3) * 8;
    const ushort_t* gb = Bt + (size_t)(n0 + wv * 32 + (l >> 2)) * K + (l & 3) * 8;

#define GSTAGE(buf_, k0_) do {                                                 \
    GLOAD16(ga + (k0_),                  &lA[buf_][wv * 1024]);                \
    GLOAD16(ga + (k0_) + (size_t)16 * K, &lA[buf_][wv * 1024 + 512]);          \
    GLOAD16(gb + (k0_),                  &lB[buf_][wv * 1024]);                \
    GLOAD16(gb + (k0_) + (size_t)16 * K, &lB[buf_][wv * 1024 + 512]);          \
} while (0)

    const int nt = K >> 5;   // assumes nt >= 2 (K >= 64)
    GSTAGE(0, 0);
    GSTAGE(1, 32);
    WAITV4;   // buf0 complete; buf1's 4 loads still in flight
    SBAR;

    for (int t = 0, cur = 0; t < nt; ++t) {
        int stg = cur + 2; if (stg >= 3) stg -= 3;
        if (t + 2 < nt) GSTAGE(stg, (t + 2) << 5);

        const ushort_t* sa = lA[cur];
        const ushort_t* sb = lB[cur];
        short8 af[4], bf[4];
        #pragma unroll
        for (int mi = 0; mi < 4; mi++)
            af[mi] = *(const short8*)(sa + (wr * 64 + mi * 16 + q16) * 32 + g * 8);
        #pragma unroll
        for (int ni = 0; ni < 4; ni++)
            bf[ni] = *(const short8*)(sb + (wc * 64 + ni * 16 + q16) * 32 + g * 8);
        #pragma unroll
        for (int mi = 0; mi < 4; mi++)
            #pragma unroll
            for (int ni = 0; ni < 4; ni++)
                acc[mi][ni] = MFMA(af[mi], bf[ni], acc[mi][ni]);

        if (t + 1 < nt) {
            // buf[t+1] must be ready; buf[t+2]'s 4 loads may stay in flight.
            if (t + 2 < nt) { WAITV4; } else { WAITV0; }
            SBAR;
        }
        ++cur; if (cur == 3) cur = 0;
    }

    #pragma unroll
    for (int ni = 0; ni < 4; ni++) {
        const int n = n0 + wc * 64 + ni * 16 + q16;
        float bv = 0.f;
        if (BIAS) bv = bias[n];
        #pragma unroll
        for (int mi = 0; mi < 4; mi++) {
            const int mbase = m0 + wr * 64 + mi * 16 + g * 4;
            #pragma unroll
            for (int r = 0; r < 4; r++) {
                if (F32OUT) {
                    ((float*)Cout)[(size_t)(mbase + r) * N + n] = acc[mi][ni][r] + bv;
                } else {
                    ((ushort_t*)Cout)[(size_t)(mbase + r) * N + n] = f2b(acc[mi][ni][r]);
                }
            }
        }
    }
#undef GSTAGE
}

// ---------------- RoPE + reshape ----------------
// Q pre-scaled by 0.125*log2(e): attention scores land directly in exp2 domain.
// Vt written INTERLEAVED per 32-key tile: 16B unit i holds keys {4i..4i+3} (lo)
// and {16+4i..19+4i} (hi) so one LDS b128 read = one PV fragment.
__global__ void rope_scatter(const ushort_t* __restrict__ qkv,
                             const float* __restrict__ cosT, const float* __restrict__ sinT,
                             ushort_t* __restrict__ Qr, ushort_t* __restrict__ Kr,
                             ushort_t* __restrict__ Vt) {
    const float QS = 0.1803368801f;  // 0.125 * log2(e)
    int tid = blockIdx.x * 256 + threadIdx.x;
    {
        int dc = tid & 7;
        int bht = tid >> 3;
        int t = bht & 2047, bh = bht >> 11;
        int b = bh >> 4, h = bh & 15;
        size_t mrow = ((size_t)b * 2048 + t) * 3072;
        short8 qv = *(const short8*)(qkv + mrow + h * 64 + dc * 8);
        short8 kv = *(const short8*)(qkv + mrow + 1024 + h * 64 + dc * 8);
        f32x4 cv = *(const f32x4*)(cosT + t * 32 + dc * 4);
        f32x4 sv = *(const f32x4*)(sinT + t * 32 + dc * 4);
        short8 qo, ko;
        #pragma unroll
        for (int j = 0; j < 4; j++) {
            float qe = b2f((ushort_t)qv[2 * j]), qod = b2f((ushort_t)qv[2 * j + 1]);
            float ke = b2f((ushort_t)kv[2 * j]), kod = b2f((ushort_t)kv[2 * j + 1]);
            qo[2 * j]     = (short)f2b((qe * cv[j] - qod * sv[j]) * QS);
            qo[2 * j + 1] = (short)f2b((qe * sv[j] + qod * cv[j]) * QS);
            ko[2 * j]     = (short)f2b(ke * cv[j] - kod * sv[j]);
            ko[2 * j + 1] = (short)f2b(ke * sv[j] + kod * cv[j]);
        }
        *(short8*)(Qr + ((size_t)bh * 2048 + t) * 64 + dc * 8) = qo;
        *(short8*)(Kr + ((size_t)bh * 2048 + t) * 64 + dc * 8) = ko;
    }
    {
        int t = tid & 2047;
        int rest = tid >> 11;
        int dc = rest & 7, bh = rest >> 3;
        int b = bh >> 4, h = bh & 15;
        const ushort_t* vs = qkv + ((size_t)b * 2048 + t) * 3072 + 2048 + h * 64 + dc * 8;
        // interleave position within the 32-key tile
        int tp = (t & ~31) + ((t & 12) << 1) + ((t & 16) >> 2) + (t & 3);
        #pragma unroll
        for (int j = 0; j < 8; j++)
            Vt[((size_t)bh * 64 + dc * 8 + j) * 2048 + tp] = vs[j];
    }
}

// ---------------- causal flash attention ----------------
// KVBLK=64, LDS-staged K/V shared by 4 lockstep waves, double-buffered.
// K_lds [64 key][128B]: 16B slot s of row k holds d-unit s ^ (k&7)  -> b128 @ 2-way floor.
// V_lds [2 half][64 d][64B]: slot s of row d holds key-unit s ^ ((d>>1)&3) of the
//   interleaved global layout -> b128 @ 2-way floor, fragment ready (no repack).
// Pairing p = 4*slot + wv: the 4 waves of a block differ by <=1 lockstep iter.
// Static-max softmax: scores already in exp2 domain, p = exp2(s) directly.

__device__ __forceinline__ void tile64(
    const f32x4& S0, const f32x4& S1, const f32x4& S2, const f32x4& S3,
    int qpos, bool msk, int kvb, int g, float& ls,
    f32x4& o0, f32x4& o1, f32x4& o2, f32x4& o3,
    const short8& va0, const short8& va1, const short8& va2, const short8& va3,
    const short8& vb0, const short8& vb1, const short8& vb2, const short8& vb3) {
    float sv[16];
    #pragma unroll
    for (int r = 0; r < 4; r++) {
        sv[r] = S0[r]; sv[4 + r] = S1[r]; sv[8 + r] = S2[r]; sv[12 + r] = S3[r];
    }
    if (msk) {
        int kb0 = kvb + (g << 2);
        #pragma unroll
        for (int G = 0; G < 4; G++)
            #pragma unroll
            for (int r = 0; r < 4; r++)
                if (kb0 + 16 * G + r > qpos) sv[G * 4 + r] = -INFINITY;
    }
    float pp[16];
    #pragma unroll
    for (int i = 0; i < 16; i++) pp[i] = __builtin_amdgcn_exp2f(sv[i]);
    ls += (((pp[0] + pp[1]) + (pp[2] + pp[3])) + ((pp[4] + pp[5]) + (pp[6] + pp[7]))) +
          (((pp[8] + pp[9]) + (pp[10] + pp[11])) + ((pp[12] + pp[13]) + (pp[14] + pp[15])));
    union { short8 s; unsigned u[4]; } p0, p1;
    asm("v_cvt_pk_bf16_f32 %0, %1, %2" : "=v"(p0.u[0]) : "v"(pp[0]), "v"(pp[1]));
    asm("v_cvt_pk_bf16_f32 %0, %1, %2" : "=v"(p0.u[1]) : "v"(pp[2]), "v"(pp[3]));
    asm("v_cvt_pk_bf16_f32 %0, %1, %2" : "=v"(p0.u[2]) : "v"(pp[4]), "v"(pp[5]));
    asm("v_cvt_pk_bf16_f32 %0, %1, %2" : "=v"(p0.u[3]) : "v"(pp[6]), "v"(pp[7]));
    asm("v_cvt_pk_bf16_f32 %0, %1, %2" : "=v"(p1.u[0]) : "v"(pp[8]), "v"(pp[9]));
    asm("v_cvt_pk_bf16_f32 %0, %1, %2" : "=v"(p1.u[1]) : "v"(pp[10]), "v"(pp[11]));
    asm("v_cvt_pk_bf16_f32 %0, %1, %2" : "=v"(p1.u[2]) : "v"(pp[12]), "v"(pp[13]));
    asm("v_cvt_pk_bf16_f32 %0, %1, %2" : "=v"(p1.u[3]) : "v"(pp[14]), "v"(pp[15]));
    o0 = MFMA(va0, p0.s, o0); o0 = MFMA(vb0, p1.s, o0);
    o1 = MFMA(va1, p0.s, o1); o1 = MFMA(vb1, p1.s, o1);
    o2 = MFMA(va2, p0.s, o2); o2 = MFMA(vb2, p1.s, o2);
    o3 = MFMA(va3, p0.s, o3); o3 = MFMA(vb3, p1.s, o3);
}

#define EPI(LS, O0, O1, O2, O3, QPOS) do {                                     \
    float l2_ = LS + __shfl_xor(LS, 16);                                       \
    l2_ += __shfl_xor(l2_, 32);                                                \
    float ri_ = 1.0f / l2_;                                                    \
    ushort_t* op_ = Aout + ((size_t)(bq * 2048 + (QPOS)) << 10) + (h << 6) + (g << 2); \
    u16x4 o_;                                                                  \
    o_[0] = f2b(O0[0] * ri_); o_[1] = f2b(O0[1] * ri_);                        \
    o_[2] = f2b(O0[2] * ri_); o_[3] = f2b(O0[3] * ri_);                        \
    *(u16x4*)op_ = o_;                                                         \
    o_[0] = f2b(O1[0] * ri_); o_[1] = f2b(O1[1] * ri_);                        \
    o_[2] = f2b(O1[2] * ri_); o_[3] = f2b(O1[3] * ri_);                        \
    *(u16x4*)(op_ + 16) = o_;                                                  \
    o_[0] = f2b(O2[0] * ri_); o_[1] = f2b(O2[1] * ri_);                        \
    o_[2] = f2b(O2[2] * ri_); o_[3] = f2b(O2[3] * ri_);                        \
    *(u16x4*)(op_ + 32) = o_;                                                  \
    o_[0] = f2b(O3[0] * ri_); o_[1] = f2b(O3[1] * ri_);                        \
    o_[2] = f2b(O3[2] * ri_); o_[3] = f2b(O3[3] * ri_);                        \
    *(u16x4*)(op_ + 48) = o_;                                                  \
} while (0)

__global__ __launch_bounds__(256, 2) void attn_fwd(const ushort_t* __restrict__ Qr,
                                                   const ushort_t* __restrict__ Kr,
                                                   const ushort_t* __restrict__ Vt,
                                                   ushort_t* __restrict__ Aout) {
    __shared__ __attribute__((aligned(16))) ushort_t Ksh[2][4096]; // [64 key][128B] swz
    __shared__ __attribute__((aligned(16))) ushort_t Vsh[2][4096]; // [2 half][64 d][64B] swz

    const int tid = threadIdx.x;
    const int l = tid & 63, wv = tid >> 6;
    const int g = l >> 4, q16 = l & 15;
    // XCD-aware: each XCD owns 4 whole heads (2MB K/V fits 4MB per-XCD L2).
    const int xcd = blockIdx.x & 7, loc = blockIdx.x >> 3;
    const int h2 = loc >> 4;
    const int bh = (xcd << 2) | h2;
    int slot = loc & 15;
    if (h2 & 2) slot = 15 - slot;   // complementary pairing across round-robin wrap
    const int p = slot * 4 + wv;                  // 0..63
    const int qlo = p << 4, qhi = (127 - p) << 4; // paired q-tiles
    const int qpos_l = qlo + q16, qpos_h = qhi + q16;
    const int bq = bh >> 4, h = bh & 15;

    const int ntot_bk = (((127 - slot * 4) << 4) + 79) >> 6; // block lockstep iters
    const int ntot_w  = (qhi + 79) >> 6;                     // own hi-tile iters
    const int nlo_w   = (qlo + 79) >> 6;                     // iters with lo tile live

    const ushort_t* Qp = Qr + ((size_t)bh * 2048) * 64;
    short8 ql0 = *(const short8*)(Qp + (size_t)qpos_l * 64 + g * 8);
    short8 ql1 = *(const short8*)(Qp + (size_t)qpos_l * 64 + g * 8 + 32);
    short8 qh0 = *(const short8*)(Qp + (size_t)qpos_h * 64 + g * 8);
    short8 qh1 = *(const short8*)(Qp + (size_t)qpos_h * 64 + g * 8 + 32);

    const ushort_t* Kb = Kr + (size_t)bh * 2048 * 64;
    const ushort_t* Vb = Vt + (size_t)bh * 64 * 2048;

    // staging sources (pre-swizzled so the linear LDS dest realizes the XOR)
    const ushort_t* ksrcA = Kb + (size_t)(wv * 16 + (l >> 3)) * 64 + (((l & 7) ^ (l >> 3)) << 3);
    const ushort_t* vsrcA = Vb + (size_t)(wv * 16 + (l >> 2)) * 2048 + (((l & 3) ^ ((l >> 3) & 3)) << 3);

#define STAGE(buf_, t_) do {                                                   \
    const ushort_t* ka_ = ksrcA + (size_t)(t_) * 4096;                         \
    const ushort_t* va_ = vsrcA + (t_) * 64;                                   \
    GLOAD16(ka_,       &Ksh[buf_][wv * 1024]);                                 \
    GLOAD16(ka_ + 512, &Ksh[buf_][wv * 1024 + 512]);                           \
    GLOAD16(va_,       &Vsh[buf_][wv * 512]);                                  \
    GLOAD16(va_ + 32,  &Vsh[buf_][2048 + wv * 512]);                           \
} while (0)

    // read-side swizzled byte offsets
    const int kx  = q16 & 7;
    const int kq  = q16 * 128;
    const int kh0 = (g ^ kx) << 4;
    const int kh1 = ((g + 4) ^ kx) << 4;
    const int vsw = (g ^ ((q16 >> 1) & 3)) << 4;
    const int vq  = q16 * 64;

    float ls_l = 0.f, ls_h = 0.f;
    f32x4 ol0 = {0.f,0.f,0.f,0.f}, ol1 = {0.f,0.f,0.f,0.f};
    f32x4 ol2 = {0.f,0.f,0.f,0.f}, ol3 = {0.f,0.f,0.f,0.f};
    f32x4 oh0 = {0.f,0.f,0.f,0.f}, oh1 = {0.f,0.f,0.f,0.f};
    f32x4 oh2 = {0.f,0.f,0.f,0.f}, oh3 = {0.f,0.f,0.f,0.f};

    STAGE(0, 0);
    __syncthreads();

    for (int t = 0; t < ntot_bk; ++t) {
        const int nxt = t + 1;
        if (nxt < ntot_bk) {
            if (nxt & 1) STAGE(1, nxt); else STAGE(0, nxt);
        }
        if (t < ntot_w) {
            const char* Kc = (const char*)(t & 1 ? Ksh[1] : Ksh[0]);
            const char* Vc = (const char*)(t & 1 ? Vsh[1] : Vsh[0]);
            // K fragments: group G rows kvb+16G+q16, d-halves 0/1
            short8 k00 = *(const short8*)(Kc + kq + kh0);
            short8 k01 = *(const short8*)(Kc + kq + kh1);
            short8 k10 = *(const short8*)(Kc + kq + 2048 + kh0);
            short8 k11 = *(const short8*)(Kc + kq + 2048 + kh1);
            short8 k20 = *(const short8*)(Kc + kq + 4096 + kh0);
            short8 k21 = *(const short8*)(Kc + kq + 4096 + kh1);
            short8 k30 = *(const short8*)(Kc + kq + 6144 + kh0);
            short8 k31 = *(const short8*)(Kc + kq + 6144 + kh1);
            // QK^T (swapped): rows = keys, cols = q
            f32x4 s0 = {0.f,0.f,0.f,0.f}, s1 = {0.f,0.f,0.f,0.f};
            f32x4 s2 = {0.f,0.f,0.f,0.f}, s3 = {0.f,0.f,0.f,0.f};
            s0 = MFMA(k00, qh0, s0); s0 = MFMA(k01, qh1, s0);
            s1 = MFMA(k10, qh0, s1); s1 = MFMA(k11, qh1, s1);
            s2 = MFMA(k20, qh0, s2); s2 = MFMA(k21, qh1, s2);
            s3 = MFMA(k30, qh0, s3); s3 = MFMA(k31, qh1, s3);
            const bool lo_on = t < nlo_w;
            f32x4 u0 = {0.f,0.f,0.f,0.f}, u1 = {0.f,0.f,0.f,0.f};
            f32x4 u2 = {0.f,0.f,0.f,0.f}, u3 = {0.f,0.f,0.f,0.f};
            if (lo_on) {
                u0 = MFMA(k00, ql0, u0); u0 = MFMA(k01, ql1, u0);
                u1 = MFMA(k10, ql0, u1); u1 = MFMA(k11, ql1, u1);
                u2 = MFMA(k20, ql0, u2); u2 = MFMA(k21, ql1, u2);
                u3 = MFMA(k30, ql0, u3); u3 = MFMA(k31, ql1, u3);
            }
            // V fragments: half A = keys kvb..+31, half B = keys kvb+32..+63
            short8 va0 = *(const short8*)(Vc + vq + vsw);
            short8 va1 = *(const short8*)(Vc + vq + 1024 + vsw);
            short8 va2 = *(const short8*)(Vc + vq + 2048 + vsw);
            short8 va3 = *(const short8*)(Vc + vq + 3072 + vsw);
            short8 vb0 = *(const short8*)(Vc + 4096 + vq + vsw);
            short8 vb1 = *(const short8*)(Vc + 4096 + vq + 1024 + vsw);
            short8 vb2 = *(const short8*)(Vc + 4096 + vq + 2048 + vsw);
            short8 vb3 = *(const short8*)(Vc + 4096 + vq + 3072 + vsw);
            const int kvb = t << 6;
            tile64(s0, s1, s2, s3, qpos_h, kvb + 63 > qhi, kvb, g, ls_h,
                   oh0, oh1, oh2, oh3, va0, va1, va2, va3, vb0, vb1, vb2, vb3);
            if (lo_on)
                tile64(u0, u1, u2, u3, qpos_l, kvb + 63 > qlo, kvb, g, ls_l,
                       ol0, ol1, ol2, ol3, va0, va1, va2, va3, vb0, vb1, vb2, vb3);
        }
        __syncthreads();
    }

    EPI(ls_l, ol0, ol1, ol2, ol3, qpos_l);
    EPI(ls_h, oh0, oh1, oh2, oh3, qpos_h);
#undef STAGE
}

// ---------------- launch ----------------
extern "C" void kernel_launch(void* const* d_in, const int* in_sizes, int n_in,
                              void* d_out, int out_size, void* d_ws, size_t ws_size,
                              hipStream_t stream) {
    const float* x     = (const float*)d_in[0];
    const float* Wqkv  = (const float*)d_in[1];
    const float* Wproj = (const float*)d_in[2];
    const float* bproj = (const float*)d_in[3];
    const float* cosT  = (const float*)d_in[4];
    const float* sinT  = (const float*)d_in[5];

    char* ws = (char*)d_ws;
    ushort_t* xb     = (ushort_t*)(ws);
    ushort_t* WqkvT  = (ushort_t*)(ws + (8u  << 20));
    ushort_t* WprojT = (ushort_t*)(ws + (14u << 20));
    ushort_t* qkv    = (ushort_t*)(ws + (16u << 20));
    ushort_t* Qr     = (ushort_t*)(ws + (40u << 20));
    ushort_t* Kr     = (ushort_t*)(ws + (48u << 20));
    ushort_t* Vt     = (ushort_t*)(ws + (56u << 20));
    ushort_t* aout   = (ushort_t*)(ws + (64u << 20));

    cvt_bf16<<<4096, 256, 0, stream>>>(x, xb, 4096 * 1024);
    transpose_cvt<<<dim3(96, 32), 256, 0, stream>>>(Wqkv, WqkvT, 1024, 3072);
    transpose_cvt<<<dim3(32, 32), 256, 0, stream>>>(Wproj, WprojT, 1024, 1024);

    // 1-D grids, both % 8 == 0: qkv 24x32=768 tiles, proj 8x32=256 tiles
    gemm_bt<false, false><<<768, 256, 0, stream>>>(xb, WqkvT, (void*)qkv, nullptr,
                                                   4096, 3072, 1024, 24);
    rope_scatter<<<2048, 256, 0, stream>>>(qkv, cosT, sinT, Qr, Kr, Vt);
    attn_fwd<<<512, 256, 0, stream>>>(Qr, Kr, Vt, aout);
    gemm_bt<true, true><<<256, 256, 0, stream>>>(aout, WprojT, d_out, bproj,
                                                 4096, 1024, 1024, 8);
}

// Round 9
// 184.540 us; speedup vs baseline: 1.0133x; 1.0133x over previous
//
#include <hip/hip_runtime.h>

typedef __attribute__((ext_vector_type(8))) short short8;
typedef __attribute__((ext_vector_type(4))) float f32x4;
typedef __attribute__((ext_vector_type(4))) unsigned short u16x4;
typedef unsigned short ushort_t;

#define GLOAD16(gp, sp) __builtin_amdgcn_global_load_lds( \
    (const __attribute__((address_space(1))) void*)(gp),  \
    (__attribute__((address_space(3))) void*)(sp), 16, 0, 0)

#define MFMA(a, b, c) __builtin_amdgcn_mfma_f32_16x16x32_bf16(a, b, c, 0, 0, 0)

__device__ __forceinline__ ushort_t f2b(float f) {
    union { float f; unsigned u; } c; c.f = f;
    unsigned r = (c.u + 0x7FFFu + ((c.u >> 16) & 1u)) >> 16;
    return (ushort_t)r;
}
__device__ __forceinline__ float b2f(ushort_t u) {
    union { unsigned u; float f; } c; c.u = ((unsigned)u) << 16;
    return c.f;
}

// ---------------- fp32 -> bf16 convert ----------------
__global__ void cvt_bf16(const float* __restrict__ in, ushort_t* __restrict__ out, int n) {
    int i = (blockIdx.x * 256 + threadIdx.x) * 4;
    if (i < n) {
        f32x4 v = *(const f32x4*)(in + i);
        u16x4 o;
        #pragma unroll
        for (int j = 0; j < 4; j++) o[j] = f2b(v[j]);
        *(u16x4*)(out + i) = o;
    }
}

// ---------------- fp32 [R][Cc] -> bf16 [Cc][R] transpose ----------------
__global__ __launch_bounds__(256) void transpose_cvt(const float* __restrict__ in,
                                                     ushort_t* __restrict__ out,
                                                     int R, int Cc) {
    __shared__ float tile[32][33];
    int tx = threadIdx.x & 31, ty = threadIdx.x >> 5;
    int c0 = blockIdx.x * 32, r0 = blockIdx.y * 32;
    #pragma unroll
    for (int i = 0; i < 32; i += 8)
        tile[ty + i][tx] = in[(size_t)(r0 + ty + i) * Cc + c0 + tx];
    __syncthreads();
    #pragma unroll
    for (int i = 0; i < 32; i += 8)
        out[(size_t)(c0 + ty + i) * R + r0 + tx] = f2b(tile[tx][ty + i]);
}

// ---------------- bf16 GEMM: C[M][N] = A[M][K] * Bt[N][K]^T ----------------
// 128x128 tile, BK=32, 8 waves (2x4) / 512 threads: 2x the waves/SIMD for TLP.
// 3-buffer LDS, depth-2 prefetch, counted vmcnt (WAITV2) + raw s_barrier.
// n-MAJOR XCD chunking: each XCD owns nx/8 contiguous n-cols -> its B chunk
// (<=768KB) stays L2-resident across all m; A streams once (L3-resident after
// the first XCD touches it). Kills the B-panel refetch that made gemm fetch-bound.
#define WAITV2 asm volatile("s_waitcnt vmcnt(2)" ::: "memory")
#define WAITV0 asm volatile("s_waitcnt vmcnt(0)" ::: "memory")
#define SBAR do { __builtin_amdgcn_s_barrier(); __builtin_amdgcn_sched_barrier(0); } while (0)

template <bool F32OUT, bool BIAS>
__global__ __launch_bounds__(512, 6) void gemm_bt(const ushort_t* __restrict__ A,
                                                  const ushort_t* __restrict__ Bt,
                                                  void* __restrict__ Cout,
                                                  const float* __restrict__ bias,
                                                  int M, int N, int K, int nx) {
    __shared__ ushort_t lA[3][4096];
    __shared__ ushort_t lB[3][4096];
    const int tid = threadIdx.x;
    const int l = tid & 63, wv = tid >> 6;          // 8 waves
    const int g = l >> 4, q16 = l & 15;
    // n-major XCD chunking (nx % 8 == 0)
    const int cpx = nx >> 3;
    const int xcd = blockIdx.x & 7, idx = blockIdx.x >> 3;
    const int n0 = (xcd * cpx + idx % cpx) * 128;
    const int m0 = (idx / cpx) * 128;
    const int wr = wv >> 2, wc = wv & 3;            // 2x4 wave grid

    f32x4 acc[4][2];
    #pragma unroll
    for (int i = 0; i < 4; i++)
        #pragma unroll
        for (int j = 0; j < 2; j++) acc[i][j] = (f32x4){0.f, 0.f, 0.f, 0.f};

    // wave wv stages rows [wv*16, wv*16+16) of each tile: one GLOAD16 per matrix
    const ushort_t* ga = A + (size_t)(m0 + wv * 16 + (l >> 2)) * K + (l & 3) * 8;
    const ushort_t* gb = Bt + (size_t)(n0 + wv * 16 + (l >> 2)) * K + (l & 3) * 8;

#define GSTAGE(buf_, k0_) do {                                                 \
    GLOAD16(ga + (k0_), &lA[buf_][wv * 512]);                                  \
    GLOAD16(gb + (k0_), &lB[buf_][wv * 512]);                                  \
} while (0)

    const int nt = K >> 5;   // K >= 64
    GSTAGE(0, 0);
    GSTAGE(1, 32);
    WAITV2;   // buf0 complete; buf1's 2 loads still in flight
    SBAR;

    for (int t = 0, cur = 0; t < nt; ++t) {
        int stg = cur + 2; if (stg >= 3) stg -= 3;
        if (t + 2 < nt) GSTAGE(stg, (t + 2) << 5);

        const ushort_t* sa = lA[cur];
        const ushort_t* sb = lB[cur];
        short8 af[4], bf[2];
        #pragma unroll
        for (int mi = 0; mi < 4; mi++)
            af[mi] = *(const short8*)(sa + (wr * 64 + mi * 16 + q16) * 32 + g * 8);
        #pragma unroll
        for (int ni = 0; ni < 2; ni++)
            bf[ni] = *(const short8*)(sb + (wc * 32 + ni * 16 + q16) * 32 + g * 8);
        #pragma unroll
        for (int mi = 0; mi < 4; mi++)
            #pragma unroll
            for (int ni = 0; ni < 2; ni++)
                acc[mi][ni] = MFMA(af[mi], bf[ni], acc[mi][ni]);

        if (t + 1 < nt) {
            if (t + 2 < nt) { WAITV2; } else { WAITV0; }
            SBAR;
        }
        ++cur; if (cur == 3) cur = 0;
    }

    #pragma unroll
    for (int ni = 0; ni < 2; ni++) {
        const int n = n0 + wc * 32 + ni * 16 + q16;
        float bv = 0.f;
        if (BIAS) bv = bias[n];
        #pragma unroll
        for (int mi = 0; mi < 4; mi++) {
            const int mbase = m0 + wr * 64 + mi * 16 + g * 4;
            #pragma unroll
            for (int r = 0; r < 4; r++) {
                if (F32OUT) {
                    ((float*)Cout)[(size_t)(mbase + r) * N + n] = acc[mi][ni][r] + bv;
                } else {
                    ((ushort_t*)Cout)[(size_t)(mbase + r) * N + n] = f2b(acc[mi][ni][r]);
                }
            }
        }
    }
#undef GSTAGE
}

// ---------------- RoPE + reshape ----------------
// Q pre-scaled by 0.125*log2(e): attention scores land directly in exp2 domain.
// Vt written INTERLEAVED per 32-key tile: 16B unit i holds keys {4i..4i+3} (lo)
// and {16+4i..19+4i} (hi) so one LDS b128 read = one PV fragment.
__global__ void rope_scatter(const ushort_t* __restrict__ qkv,
                             const float* __restrict__ cosT, const float* __restrict__ sinT,
                             ushort_t* __restrict__ Qr, ushort_t* __restrict__ Kr,
                             ushort_t* __restrict__ Vt) {
    const float QS = 0.1803368801f;  // 0.125 * log2(e)
    int tid = blockIdx.x * 256 + threadIdx.x;
    {
        int dc = tid & 7;
        int bht = tid >> 3;
        int t = bht & 2047, bh = bht >> 11;
        int b = bh >> 4, h = bh & 15;
        size_t mrow = ((size_t)b * 2048 + t) * 3072;
        short8 qv = *(const short8*)(qkv + mrow + h * 64 + dc * 8);
        short8 kv = *(const short8*)(qkv + mrow + 1024 + h * 64 + dc * 8);
        f32x4 cv = *(const f32x4*)(cosT + t * 32 + dc * 4);
        f32x4 sv = *(const f32x4*)(sinT + t * 32 + dc * 4);
        short8 qo, ko;
        #pragma unroll
        for (int j = 0; j < 4; j++) {
            float qe = b2f((ushort_t)qv[2 * j]), qod = b2f((ushort_t)qv[2 * j + 1]);
            float ke = b2f((ushort_t)kv[2 * j]), kod = b2f((ushort_t)kv[2 * j + 1]);
            qo[2 * j]     = (short)f2b((qe * cv[j] - qod * sv[j]) * QS);
            qo[2 * j + 1] = (short)f2b((qe * sv[j] + qod * cv[j]) * QS);
            ko[2 * j]     = (short)f2b(ke * cv[j] - kod * sv[j]);
            ko[2 * j + 1] = (short)f2b(ke * sv[j] + kod * cv[j]);
        }
        *(short8*)(Qr + ((size_t)bh * 2048 + t) * 64 + dc * 8) = qo;
        *(short8*)(Kr + ((size_t)bh * 2048 + t) * 64 + dc * 8) = ko;
    }
    {
        int t = tid & 2047;
        int rest = tid >> 11;
        int dc = rest & 7, bh = rest >> 3;
        int b = bh >> 4, h = bh & 15;
        const ushort_t* vs = qkv + ((size_t)b * 2048 + t) * 3072 + 2048 + h * 64 + dc * 8;
        // interleave position within the 32-key tile
        int tp = (t & ~31) + ((t & 12) << 1) + ((t & 16) >> 2) + (t & 3);
        #pragma unroll
        for (int j = 0; j < 8; j++)
            Vt[((size_t)bh * 64 + dc * 8 + j) * 2048 + tp] = vs[j];
    }
}

// ---------------- causal flash attention ----------------
// KVBLK=64, LDS-staged K/V shared by 4 lockstep waves, double-buffered.
// K_lds [64 key][128B]: 16B slot s of row k holds d-unit s ^ (k&7)  -> b128 @ 2-way floor.
// V_lds [2 half][64 d][64B]: slot s of row d holds key-unit s ^ ((d>>1)&3) of the
//   interleaved global layout -> b128 @ 2-way floor, fragment ready (no repack).
// Pairing p = 4*slot + wv: the 4 waves of a block differ by <=1 lockstep iter.
// Static-max softmax: scores already in exp2 domain, p = exp2(s) directly.

__device__ __forceinline__ void tile64(
    const f32x4& S0, const f32x4& S1, const f32x4& S2, const f32x4& S3,
    int qpos, bool msk, int kvb, int g, float& ls,
    f32x4& o0, f32x4& o1, f32x4& o2, f32x4& o3,
    const short8& va0, const short8& va1, const short8& va2, const short8& va3,
    const short8& vb0, const short8& vb1, const short8& vb2, const short8& vb3) {
    float sv[16];
    #pragma unroll
    for (int r = 0; r < 4; r++) {
        sv[r] = S0[r]; sv[4 + r] = S1[r]; sv[8 + r] = S2[r]; sv[12 + r] = S3[r];
    }
    if (msk) {
        int kb0 = kvb + (g << 2);
        #pragma unroll
        for (int G = 0; G < 4; G++)
            #pragma unroll
            for (int r = 0; r < 4; r++)
                if (kb0 + 16 * G + r > qpos) sv[G * 4 + r] = -INFINITY;
    }
    float pp[16];
    #pragma unroll
    for (int i = 0; i < 16; i++) pp[i] = __builtin_amdgcn_exp2f(sv[i]);
    ls += (((pp[0] + pp[1]) + (pp[2] + pp[3])) + ((pp[4] + pp[5]) + (pp[6] + pp[7]))) +
          (((pp[8] + pp[9]) + (pp[10] + pp[11])) + ((pp[12] + pp[13]) + (pp[14] + pp[15])));
    union { short8 s; unsigned u[4]; } p0, p1;
    asm("v_cvt_pk_bf16_f32 %0, %1, %2" : "=v"(p0.u[0]) : "v"(pp[0]), "v"(pp[1]));
    asm("v_cvt_pk_bf16_f32 %0, %1, %2" : "=v"(p0.u[1]) : "v"(pp[2]), "v"(pp[3]));
    asm("v_cvt_pk_bf16_f32 %0, %1, %2" : "=v"(p0.u[2]) : "v"(pp[4]), "v"(pp[5]));
    asm("v_cvt_pk_bf16_f32 %0, %1, %2" : "=v"(p0.u[3]) : "v"(pp[6]), "v"(pp[7]));
    asm("v_cvt_pk_bf16_f32 %0, %1, %2" : "=v"(p1.u[0]) : "v"(pp[8]), "v"(pp[9]));
    asm("v_cvt_pk_bf16_f32 %0, %1, %2" : "=v"(p1.u[1]) : "v"(pp[10]), "v"(pp[11]));
    asm("v_cvt_pk_bf16_f32 %0, %1, %2" : "=v"(p1.u[2]) : "v"(pp[12]), "v"(pp[13]));
    asm("v_cvt_pk_bf16_f32 %0, %1, %2" : "=v"(p1.u[3]) : "v"(pp[14]), "v"(pp[15]));
    o0 = MFMA(va0, p0.s, o0); o0 = MFMA(vb0, p1.s, o0);
    o1 = MFMA(va1, p0.s, o1); o1 = MFMA(vb1, p1.s, o1);
    o2 = MFMA(va2, p0.s, o2); o2 = MFMA(vb2, p1.s, o2);
    o3 = MFMA(va3, p0.s, o3); o3 = MFMA(vb3, p1.s, o3);
}

#define EPI(LS, O0, O1, O2, O3, QPOS) do {                                     \
    float l2_ = LS + __shfl_xor(LS, 16);                                       \
    l2_ += __shfl_xor(l2_, 32);                                                \
    float ri_ = 1.0f / l2_;                                                    \
    ushort_t* op_ = Aout + ((size_t)(bq * 2048 + (QPOS)) << 10) + (h << 6) + (g << 2); \
    u16x4 o_;                                                                  \
    o_[0] = f2b(O0[0] * ri_); o_[1] = f2b(O0[1] * ri_);                        \
    o_[2] = f2b(O0[2] * ri_); o_[3] = f2b(O0[3] * ri_);                        \
    *(u16x4*)op_ = o_;                                                         \
    o_[0] = f2b(O1[0] * ri_); o_[1] = f2b(O1[1] * ri_);                        \
    o_[2] = f2b(O1[2] * ri_); o_[3] = f2b(O1[3] * ri_);                        \
    *(u16x4*)(op_ + 16) = o_;                                                  \
    o_[0] = f2b(O2[0] * ri_); o_[1] = f2b(O2[1] * ri_);                        \
    o_[2] = f2b(O2[2] * ri_); o_[3] = f2b(O2[3] * ri_);                        \
    *(u16x4*)(op_ + 32) = o_;                                                  \
    o_[0] = f2b(O3[0] * ri_); o_[1] = f2b(O3[1] * ri_);                        \
    o_[2] = f2b(O3[2] * ri_); o_[3] = f2b(O3[3] * ri_);                        \
    *(u16x4*)(op_ + 48) = o_;                                                  \
} while (0)

__global__ __launch_bounds__(256, 2) void attn_fwd(const ushort_t* __restrict__ Qr,
                                                   const ushort_t* __restrict__ Kr,
                                                   const ushort_t* __restrict__ Vt,
                                                   ushort_t* __restrict__ Aout) {
    __shared__ __attribute__((aligned(16))) ushort_t Ksh[2][4096]; // [64 key][128B] swz
    __shared__ __attribute__((aligned(16))) ushort_t Vsh[2][4096]; // [2 half][64 d][64B] swz

    const int tid = threadIdx.x;
    const int l = tid & 63, wv = tid >> 6;
    const int g = l >> 4, q16 = l & 15;
    // XCD-aware: each XCD owns 4 whole heads (2MB K/V fits 4MB per-XCD L2).
    const int xcd = blockIdx.x & 7, loc = blockIdx.x >> 3;
    const int h2 = loc >> 4;
    const int bh = (xcd << 2) | h2;
    int slot = loc & 15;
    if (h2 & 2) slot = 15 - slot;   // complementary pairing across round-robin wrap
    const int p = slot * 4 + wv;                  // 0..63
    const int qlo = p << 4, qhi = (127 - p) << 4; // paired q-tiles
    const int qpos_l = qlo + q16, qpos_h = qhi + q16;
    const int bq = bh >> 4, h = bh & 15;

    const int ntot_bk = (((127 - slot * 4) << 4) + 79) >> 6; // block lockstep iters
    const int ntot_w  = (qhi + 79) >> 6;                     // own hi-tile iters
    const int nlo_w   = (qlo + 79) >> 6;                     // iters with lo tile live

    const ushort_t* Qp = Qr + ((size_t)bh * 2048) * 64;
    short8 ql0 = *(const short8*)(Qp + (size_t)qpos_l * 64 + g * 8);
    short8 ql1 = *(const short8*)(Qp + (size_t)qpos_l * 64 + g * 8 + 32);
    short8 qh0 = *(const short8*)(Qp + (size_t)qpos_h * 64 + g * 8);
    short8 qh1 = *(const short8*)(Qp + (size_t)qpos_h * 64 + g * 8 + 32);

    const ushort_t* Kb = Kr + (size_t)bh * 2048 * 64;
    const ushort_t* Vb = Vt + (size_t)bh * 64 * 2048;

    // staging sources (pre-swizzled so the linear LDS dest realizes the XOR)
    const ushort_t* ksrcA = Kb + (size_t)(wv * 16 + (l >> 3)) * 64 + (((l & 7) ^ (l >> 3)) << 3);
    const ushort_t* vsrcA = Vb + (size_t)(wv * 16 + (l >> 2)) * 2048 + (((l & 3) ^ ((l >> 3) & 3)) << 3);

#define STAGE(buf_, t_) do {                                                   \
    const ushort_t* ka_ = ksrcA + (size_t)(t_) * 4096;                         \
    const ushort_t* va_ = vsrcA + (t_) * 64;                                   \
    GLOAD16(ka_,       &Ksh[buf_][wv * 1024]);                                 \
    GLOAD16(ka_ + 512, &Ksh[buf_][wv * 1024 + 512]);                           \
    GLOAD16(va_,       &Vsh[buf_][wv * 512]);                                  \
    GLOAD16(va_ + 32,  &Vsh[buf_][2048 + wv * 512]);                           \
} while (0)

    // read-side swizzled byte offsets
    const int kx  = q16 & 7;
    const int kq  = q16 * 128;
    const int kh0 = (g ^ kx) << 4;
    const int kh1 = ((g + 4) ^ kx) << 4;
    const int vsw = (g ^ ((q16 >> 1) & 3)) << 4;
    const int vq  = q16 * 64;

    float ls_l = 0.f, ls_h = 0.f;
    f32x4 ol0 = {0.f,0.f,0.f,0.f}, ol1 = {0.f,0.f,0.f,0.f};
    f32x4 ol2 = {0.f,0.f,0.f,0.f}, ol3 = {0.f,0.f,0.f,0.f};
    f32x4 oh0 = {0.f,0.f,0.f,0.f}, oh1 = {0.f,0.f,0.f,0.f};
    f32x4 oh2 = {0.f,0.f,0.f,0.f}, oh3 = {0.f,0.f,0.f,0.f};

    STAGE(0, 0);
    __syncthreads();

    for (int t = 0; t < ntot_bk; ++t) {
        const int nxt = t + 1;
        if (nxt < ntot_bk) {
            if (nxt & 1) STAGE(1, nxt); else STAGE(0, nxt);
        }
        if (t < ntot_w) {
            const char* Kc = (const char*)(t & 1 ? Ksh[1] : Ksh[0]);
            const char* Vc = (const char*)(t & 1 ? Vsh[1] : Vsh[0]);
            // K fragments: group G rows kvb+16G+q16, d-halves 0/1
            short8 k00 = *(const short8*)(Kc + kq + kh0);
            short8 k01 = *(const short8*)(Kc + kq + kh1);
            short8 k10 = *(const short8*)(Kc + kq + 2048 + kh0);
            short8 k11 = *(const short8*)(Kc + kq + 2048 + kh1);
            short8 k20 = *(const short8*)(Kc + kq + 4096 + kh0);
            short8 k21 = *(const short8*)(Kc + kq + 4096 + kh1);
            short8 k30 = *(const short8*)(Kc + kq + 6144 + kh0);
            short8 k31 = *(const short8*)(Kc + kq + 6144 + kh1);
            // QK^T (swapped): rows = keys, cols = q
            f32x4 s0 = {0.f,0.f,0.f,0.f}, s1 = {0.f,0.f,0.f,0.f};
            f32x4 s2 = {0.f,0.f,0.f,0.f}, s3 = {0.f,0.f,0.f,0.f};
            s0 = MFMA(k00, qh0, s0); s0 = MFMA(k01, qh1, s0);
            s1 = MFMA(k10, qh0, s1); s1 = MFMA(k11, qh1, s1);
            s2 = MFMA(k20, qh0, s2); s2 = MFMA(k21, qh1, s2);
            s3 = MFMA(k30, qh0, s3); s3 = MFMA(k31, qh1, s3);
            const bool lo_on = t < nlo_w;
            f32x4 u0 = {0.f,0.f,0.f,0.f}, u1 = {0.f,0.f,0.f,0.f};
            f32x4 u2 = {0.f,0.f,0.f,0.f}, u3 = {0.f,0.f,0.f,0.f};
            if (lo_on) {
                u0 = MFMA(k00, ql0, u0); u0 = MFMA(k01, ql1, u0);
                u1 = MFMA(k10, ql0, u1); u1 = MFMA(k11, ql1, u1);
                u2 = MFMA(k20, ql0, u2); u2 = MFMA(k21, ql1, u2);
                u3 = MFMA(k30, ql0, u3); u3 = MFMA(k31, ql1, u3);
            }
            // V fragments: half A = keys kvb..+31, half B = keys kvb+32..+63
            short8 va0 = *(const short8*)(Vc + vq + vsw);
            short8 va1 = *(const short8*)(Vc + vq + 1024 + vsw);
            short8 va2 = *(const short8*)(Vc + vq + 2048 + vsw);
            short8 va3 = *(const short8*)(Vc + vq + 3072 + vsw);
            short8 vb0 = *(const short8*)(Vc + 4096 + vq + vsw);
            short8 vb1 = *(const short8*)(Vc + 4096 + vq + 1024 + vsw);
            short8 vb2 = *(const short8*)(Vc + 4096 + vq + 2048 + vsw);
            short8 vb3 = *(const short8*)(Vc + 4096 + vq + 3072 + vsw);
            const int kvb = t << 6;
            tile64(s0, s1, s2, s3, qpos_h, kvb + 63 > qhi, kvb, g, ls_h,
                   oh0, oh1, oh2, oh3, va0, va1, va2, va3, vb0, vb1, vb2, vb3);
            if (lo_on)
                tile64(u0, u1, u2, u3, qpos_l, kvb + 63 > qlo, kvb, g, ls_l,
                       ol0, ol1, ol2, ol3, va0, va1, va2, va3, vb0, vb1, vb2, vb3);
        }
        __syncthreads();
    }

    EPI(ls_l, ol0, ol1, ol2, ol3, qpos_l);
    EPI(ls_h, oh0, oh1, oh2, oh3, qpos_h);
#undef STAGE
}

// ---------------- launch ----------------
extern "C" void kernel_launch(void* const* d_in, const int* in_sizes, int n_in,
                              void* d_out, int out_size, void* d_ws, size_t ws_size,
                              hipStream_t stream) {
    const float* x     = (const float*)d_in[0];
    const float* Wqkv  = (const float*)d_in[1];
    const float* Wproj = (const float*)d_in[2];
    const float* bproj = (const float*)d_in[3];
    const float* cosT  = (const float*)d_in[4];
    const float* sinT  = (const float*)d_in[5];

    char* ws = (char*)d_ws;
    ushort_t* xb     = (ushort_t*)(ws);
    ushort_t* WqkvT  = (ushort_t*)(ws + (8u  << 20));
    ushort_t* WprojT = (ushort_t*)(ws + (14u << 20));
    ushort_t* qkv    = (ushort_t*)(ws + (16u << 20));
    ushort_t* Qr     = (ushort_t*)(ws + (40u << 20));
    ushort_t* Kr     = (ushort_t*)(ws + (48u << 20));
    ushort_t* Vt     = (ushort_t*)(ws + (56u << 20));
    ushort_t* aout   = (ushort_t*)(ws + (64u << 20));

    cvt_bf16<<<4096, 256, 0, stream>>>(x, xb, 4096 * 1024);
    transpose_cvt<<<dim3(96, 32), 256, 0, stream>>>(Wqkv, WqkvT, 1024, 3072);
    transpose_cvt<<<dim3(32, 32), 256, 0, stream>>>(Wproj, WprojT, 1024, 1024);

    // 1-D grids, both % 8 == 0: qkv 24x32=768 tiles, proj 8x32=256 tiles
    gemm_bt<false, false><<<768, 512, 0, stream>>>(xb, WqkvT, (void*)qkv, nullptr,
                                                   4096, 3072, 1024, 24);
    rope_scatter<<<2048, 256, 0, stream>>>(qkv, cosT, sinT, Qr, Kr, Vt);
    attn_fwd<<<512, 256, 0, stream>>>(Qr, Kr, Vt, aout);
    gemm_bt<true, true><<<256, 512, 0, stream>>>(aout, WprojT, d_out, bproj,
                                                 4096, 1024, 1024, 8);
}